// Round 7
// baseline (1241.630 us; speedup 1.0000x reference)
//
#include <hip/hip_runtime.h>
#include <math.h>
#include <stdio.h>

#define N_NODES 16384
#define DIM     512
#define BSZ     16
#define SEQ     1024
#define MCTX    256
#define NHEAD   8
#define DHEAD   64
#define NLAYER  4
#define NEDGE   262144
#define DFF     2048
#define DG      4096
#define LNEPS   1e-5f

typedef unsigned short u16;
typedef __attribute__((ext_vector_type(8))) __bf16 bf16x8;
typedef __attribute__((ext_vector_type(4))) float f32x4;
typedef __attribute__((ext_vector_type(4))) unsigned short u16x4;
typedef __attribute__((ext_vector_type(8))) unsigned short u16x8;

__device__ __forceinline__ u16 f2b(float f) {
    unsigned u = __float_as_uint(f);
    unsigned r = (u + 0x7fff + ((u >> 16) & 1)) >> 16;
    return (u16)r;
}
__device__ __forceinline__ float b2f(u16 h) {
    return __uint_as_float((unsigned)h << 16);
}
__device__ __forceinline__ float gelu_exact(float x) {
    return 0.5f * x * (1.0f + erff(x * 0.70710678118654752f));
}
// tanh-approx gelu via hardware exp; |err| vs exact < 2e-3
__device__ __forceinline__ float gelu_fast(float x) {
    float u = x * (0.7978845608f + 0.0356774081f * x * x);
    float e = __expf(2.f * u);
    float t = 1.f - 2.f / (e + 1.f);
    return 0.5f * x * (1.f + t);
}
__device__ __forceinline__ void gload16(const void* g, void* l) {
    __builtin_amdgcn_global_load_lds(
        (const __attribute__((address_space(1))) unsigned int*)g,
        (__attribute__((address_space(3))) unsigned int*)l, 16, 0, 0);
}

// bijective XCD-chunk swizzle (m204)
__device__ __forceinline__ int2 xcd_map() {
    int gx = gridDim.x, gy = gridDim.y;
    int nwg = gx * gy;
    int id = blockIdx.y * gx + blockIdx.x;
    int q = nwg >> 3, r = nwg & 7;
    int xcd = id & 7, idx = id >> 3;
    int nid = (xcd < r ? xcd * (q + 1) : r * (q + 1) + (xcd - r) * q) + idx;
    int2 o; o.x = nid % gx; o.y = nid / gx; return o;
}

// ---------------------------------------------------------------------------
// 256x256 2-FAT-PHASE bf16 GEMM with fused GEGLU epilogue (pair-interleaved W).
// Phase X: read A-P0 + ALL B (16 ds_read_b128), stage kt+1 half2, 32 MFMA.
// Phase Y: read A-P1 (B reg-carried),  stage kt+2 half1, 32 MFMA, vmcnt(4).
// Region-disjoint staging vs reads; counted vmcnt never 0 in steady state.
// Epilogue: per-wave LDS bounce -> coalesced u16x8 stores (256B segments).
// ---------------------------------------------------------------------------
__global__ __launch_bounds__(512, 2) void bgemm256_geglu(
    const u16* __restrict__ A, long lda,
    const u16* __restrict__ Bt, long ldb,
    const float* __restrict__ bias,
    u16* __restrict__ Cb, int K)
{
    __shared__ u16 lds[65536];   // A0 A1 B0 B1, 32KB each (u16 offsets 16384)

    const int t = threadIdx.x;
    const int w = t >> 6, lane = t & 63;
    const int fr = lane & 15, fq = lane >> 4;
    int2 sw = xcd_map();
    const int row0 = sw.y * 256;
    const int col0 = sw.x * 256;
    const int wm0 = (w >> 2) * 128, wn0 = (w & 3) * 64;
    const int sl = (lane & 7) ^ ((lane >> 3) & 7);   // src slot for staging

    f32x4 acc[8][4];
#pragma unroll
    for (int mf = 0; mf < 8; ++mf)
#pragma unroll
        for (int nf = 0; nf < 4; ++nf) acc[mf][nf] = (f32x4){0.f, 0.f, 0.f, 0.f};

    auto stageA = [&](int kt_, int P, int bb) {
        const int k0 = kt_ << 6;
#pragma unroll
        for (int rd = 0; rd < 2; ++rd) {
            int rbase = rd * 128 + P * 64 + w * 8;            // wave-uniform
            int r = rbase + (lane >> 3);
            gload16(A + (size_t)(row0 + r) * lda + k0 + sl * 8,
                    (char*)(lds + bb * 16384) + rbase * 128);
        }
    };
    auto stageB = [&](int kt_, int Q, int bb) {
        const int k0 = kt_ << 6;
#pragma unroll
        for (int rd = 0; rd < 2; ++rd) {
            int jb = rd * 64 + w * 8;
            int nbase = ((jb >> 5) << 6) + Q * 32 + (jb & 31); // wave-uniform
            int n = nbase + (lane >> 3);
            gload16(Bt + (size_t)(col0 + n) * ldb + k0 + sl * 8,
                    (char*)(lds + 32768 + bb * 16384) + nbase * 128);
        }
    };

#define READ_A(MH, DST) do {                                                   \
    _Pragma("unroll")                                                          \
    for (int mi = 0; mi < 4; ++mi) {                                           \
        int r = wm0 + (MH) * 64 + mi * 16 + fr;                                \
        _Pragma("unroll")                                                      \
        for (int ks = 0; ks < 2; ++ks)                                         \
            DST[mi][ks] = *(const bf16x8*)&Ab_[r * 64 + (((ks*4+fq) ^ (fr&7)) * 8)]; \
    } } while (0)
#define READ_B_ALL(DST) do {                                                   \
    _Pragma("unroll")                                                          \
    for (int ni = 0; ni < 4; ++ni) {                                           \
        int n = wn0 + ni * 16 + fr;                                            \
        _Pragma("unroll")                                                      \
        for (int ks = 0; ks < 2; ++ks)                                         \
            DST[ni][ks] = *(const bf16x8*)&Bb_[n * 64 + (((ks*4+fq) ^ (fr&7)) * 8)]; \
    } } while (0)
#define MFMA32(MH, AV, BV)                                                     \
    _Pragma("unroll")                                                          \
    for (int mi = 0; mi < 4; ++mi)                                             \
        _Pragma("unroll")                                                      \
        for (int ni = 0; ni < 4; ++ni)                                         \
            _Pragma("unroll")                                                  \
            for (int ks = 0; ks < 2; ++ks)                                     \
                acc[(MH)*4+mi][ni] = __builtin_amdgcn_mfma_f32_16x16x32_bf16(  \
                    AV[mi][ks], BV[ni][ks], acc[(MH)*4+mi][ni], 0, 0, 0)

    // prologue: tile0 all regions (8 loads) + tile1 half1 (A-P0,B-Q0: 4 loads)
    stageA(0, 0, 0); stageB(0, 0, 0); stageA(0, 1, 0); stageB(0, 1, 0);
    stageA(1, 0, 1); stageB(1, 0, 1);
    asm volatile("s_waitcnt vmcnt(4)" ::: "memory");
    __builtin_amdgcn_s_barrier();

    const int NT = K >> 6;
    for (int kt = 0; kt < NT; ++kt) {
        const int b = kt & 1;
        const bool s1 = (kt + 1 < NT), s2 = (kt + 2 < NT);
        const u16* Ab_ = lds + b * 16384;
        const u16* Bb_ = lds + 32768 + b * 16384;
        bf16x8 av[4][2], bv[4][2];

        // phase X: A-P0 + all B; stage kt+1 half2 into b^1
        READ_A(0, av); READ_B_ALL(bv);
        if (s1) { stageA(kt + 1, 1, b ^ 1); stageB(kt + 1, 1, b ^ 1); }
        __builtin_amdgcn_s_barrier();
        asm volatile("s_waitcnt lgkmcnt(0)" ::: "memory");
        __builtin_amdgcn_s_setprio(1);
        MFMA32(0, av, bv);
        __builtin_amdgcn_s_setprio(0);
        __builtin_amdgcn_s_barrier();

        // phase Y: A-P1 (disjoint from kt+2's A-P0 staging); B reg-carried
        READ_A(1, av);
        if (s2) { stageA(kt + 2, 0, b); stageB(kt + 2, 0, b); }
        __builtin_amdgcn_s_barrier();
        asm volatile("s_waitcnt lgkmcnt(0)" ::: "memory");
        __builtin_amdgcn_s_setprio(1);
        MFMA32(1, av, bv);
        __builtin_amdgcn_s_setprio(0);
        if (s2)      asm volatile("s_waitcnt vmcnt(4)" ::: "memory");
        else if (s1) asm volatile("s_waitcnt vmcnt(0)" ::: "memory");
        __builtin_amdgcn_s_barrier();
    }
#undef READ_A
#undef READ_B_ALL
#undef MFMA32

    // fused GEGLU epilogue: acc[mf][2P]=val frag, acc[mf][2P+1]=gate frag.
    // Per-wave LDS bounce, then block-cooperative coalesced stores.
    const int nbase = (col0 + wn0) >> 1;
    float bval[2], bgat[2];
#pragma unroll
    for (int P = 0; P < 2; ++P) {
        int n = nbase + P * 16 + fr;
        bval[P] = bias[n];
        bgat[P] = bias[DFF + n];
    }
    {
        u16* Tw = lds + w * 8192;   // wave tile: 128 rows x 32 cols
#pragma unroll
        for (int mf = 0; mf < 8; ++mf)
#pragma unroll
            for (int P = 0; P < 2; ++P)
#pragma unroll
                for (int j = 0; j < 4; ++j) {
                    float v = acc[mf][2 * P][j] + bval[P];
                    float g = acc[mf][2 * P + 1][j] + bgat[P];
                    Tw[(mf * 16 + fq * 4 + j) * 32 + P * 16 + fr] =
                        f2b(v * gelu_fast(g));
                }
    }
    __syncthreads();
    const long cb0 = col0 >> 1;
#pragma unroll
    for (int i = 0; i < 8; ++i) {
        int chunk = i * 512 + t;           // 0..4095
        int r = chunk >> 4;                // 0..255
        int c8 = (chunk & 15) * 8;         // 0..120
        int sw_ = (r >> 7) * 4 + (c8 >> 5);
        u16x8 v = *(const u16x8*)&lds[sw_ * 8192 + (r & 127) * 32 + (c8 & 31)];
        *(u16x8*)&Cb[(size_t)(row0 + r) * DFF + cb0 + c8] = v;
    }
}

// ---------------------------------------------------------------------------
// bf16 MFMA GEMM, 128x128 tile, BK=64, double-buffered LDS, XCD swizzle.
// EPI: 1 = bf16 out (+bias) ; 2 = f32 out = acc+bias+resid ;
//      3 = V-transpose (LDS bounce -> Vt[z][b][h][d][m]) ; 4 = bf16 rowscale
// ---------------------------------------------------------------------------
template<int EPI>
__global__ __launch_bounds__(256) void bgemm(
    const u16* __restrict__ A, long lda,
    const u16* __restrict__ Bt, long ldb,
    const float* __restrict__ bias,
    const float* __restrict__ resid, long ldr,
    const float* __restrict__ rowscale,
    void* __restrict__ Cv, long ldc, int K, int nlo,
    long aHi, long aLo, long bHi, long bLo, long cHi, long cLo)
{
    __shared__ u16 lds[32768];    // A0 | A1 | B0 | B1, 16KB each

    const int t = threadIdx.x;
    const int z = blockIdx.z;
    const int zhi = z / nlo, zlo = z % nlo;
    const u16* Ag = A + (size_t)zhi * aHi + (size_t)zlo * aLo;
    const u16* Bg = Bt + (size_t)zhi * bHi + (size_t)zlo * bLo;
    const long coff = (long)zhi * cHi + (long)zlo * cLo;

    int2 sw = xcd_map();
    const int row0 = sw.y * 128;
    const int col0 = sw.x * 128;
    const int wave = t >> 6, lane = t & 63;
    const int wm0 = (wave >> 1) * 64, wn0 = (wave & 1) * 64;
    const int fr = lane & 15, fq = lane >> 4;
    const int ldsWave = (t & 192) * 16;
    const int rS = t >> 3;
    const int slotP = t & 7;

    f32x4 acc[4][4];
#pragma unroll
    for (int mi = 0; mi < 4; ++mi)
#pragma unroll
        for (int ni = 0; ni < 4; ++ni) acc[mi][ni] = (f32x4){0.f, 0.f, 0.f, 0.f};

    auto stage = [&](int buf, int k0) {
        u16* Ad = lds + buf * 8192;
        u16* Bd = lds + 16384 + buf * 8192;
#pragma unroll
        for (int i = 0; i < 4; ++i) {
            int r = i * 32 + rS;
            int s2 = slotP ^ (r & 7);
            gload16(Ag + (size_t)(row0 + r) * lda + k0 + s2 * 8,
                    (char*)Ad + i * 4096 + ldsWave);
        }
#pragma unroll
        for (int i = 0; i < 4; ++i) {
            int r = i * 32 + rS;
            int s2 = slotP ^ (r & 7);
            gload16(Bg + (size_t)(col0 + r) * ldb + k0 + s2 * 8,
                    (char*)Bd + i * 4096 + ldsWave);
        }
    };
    auto compute = [&](int buf) {
        const u16* Ac = lds + buf * 8192;
        const u16* Bc = lds + 16384 + buf * 8192;
#pragma unroll
        for (int ks = 0; ks < 2; ++ks) {
            const int ksl = ks * 4 + fq;
            bf16x8 av[4], bv[4];
#pragma unroll
            for (int mi = 0; mi < 4; ++mi) {
                int r = wm0 + mi * 16 + fr;
                av[mi] = *(const bf16x8*)&Ac[r * 64 + ((ksl ^ (r & 7)) * 8)];
            }
#pragma unroll
            for (int ni = 0; ni < 4; ++ni) {
                int r = wn0 + ni * 16 + fr;
                bv[ni] = *(const bf16x8*)&Bc[r * 64 + ((ksl ^ (r & 7)) * 8)];
            }
#pragma unroll
            for (int mi = 0; mi < 4; ++mi)
#pragma unroll
                for (int ni = 0; ni < 4; ++ni)
                    acc[mi][ni] = __builtin_amdgcn_mfma_f32_16x16x32_bf16(
                        av[mi], bv[ni], acc[mi][ni], 0, 0, 0);
        }
    };

    int cur = 0;
    stage(0, 0);
    __syncthreads();
    for (int k0 = 64; k0 < K; k0 += 64) {
        stage(cur ^ 1, k0);
        compute(cur);
        __syncthreads();
        cur ^= 1;
    }
    compute(cur);

    if (EPI == 3) {
        __syncthreads();
        u16* Tw = lds + wave * 4608;   // 64 x 72
#pragma unroll
        for (int mi = 0; mi < 4; ++mi)
#pragma unroll
            for (int ni = 0; ni < 4; ++ni)
#pragma unroll
                for (int j = 0; j < 4; ++j)
                    Tw[(ni * 16 + fr) * 72 + mi * 16 + fq * 4 + j] =
                        f2b(acc[mi][ni][j]);
        const int r0w = row0 + wm0;
        const int b = r0w >> 8, m0w = r0w & 255;
        const int cc0 = col0 + wn0, hh = cc0 >> 6;
        u16* dst = (u16*)Cv + coff + ((size_t)(b * 8 + hh) * 64) * 256 + m0w;
#pragma unroll
        for (int it = 0; it < 8; ++it) {
            int dl = it * 8 + (lane >> 3);
            int ml = (lane & 7) * 8;
            u16x8 v = *(const u16x8*)&Tw[dl * 72 + ml];
            *(u16x8*)&dst[(size_t)dl * 256 + ml] = v;
        }
        return;
    }

    float* Cf = (float*)Cv;
    u16* Cb = (u16*)Cv;
#pragma unroll
    for (int mi = 0; mi < 4; ++mi) {
        const int rb = row0 + wm0 + mi * 16 + fq * 4;
#pragma unroll
        for (int ni = 0; ni < 4; ++ni) {
            const int cc = col0 + wn0 + ni * 16 + fr;
            f32x4 v = acc[mi][ni];
            float bval = 0.f;
            if ((EPI == 1 || EPI == 2) && bias) bval = bias[cc];
#pragma unroll
            for (int j = 0; j < 4; ++j) {
                const long r = rb + j;
                float o = v[j] + bval;
                if (EPI == 1) {
                    Cb[coff + r * ldc + cc] = f2b(o);
                } else if (EPI == 2) {
                    Cf[coff + r * ldc + cc] = o + resid[r * ldr + cc];
                } else if (EPI == 4) {
                    Cb[coff + r * ldc + cc] = f2b(o * rowscale[r]);
                }
            }
        }
    }
}

// ---------------------------------------------------------------------------
// Batched weight transpose+convert: src f32 [K][N] -> dst bf16 [N][K].
// permN > 0: GEGLU frag-pair interleave — val n -> (n/16)*32 + n%16,
//            gate m=n-permN -> (m/16)*32 + 16 + m%16
// ---------------------------------------------------------------------------
__global__ __launch_bounds__(256) void transposeW(const float* __restrict__ src,
                                                  u16* __restrict__ dst,
                                                  int K, int N,
                                                  long srcZ, long dstZ, int permN)
{
    __shared__ float tile[64][65];
    const int t = threadIdx.x;
    const int n0 = blockIdx.x * 64, k0 = blockIdx.y * 64;
    const float* s = src + (size_t)blockIdx.z * srcZ;
    u16* d = dst + (size_t)blockIdx.z * dstZ;
#pragma unroll
    for (int i = 0; i < 16; ++i) {
        int idx = i * 256 + t;
        int rr = idx >> 6, cc = idx & 63;
        tile[rr][cc] = s[(size_t)(k0 + rr) * N + n0 + cc];
    }
    __syncthreads();
#pragma unroll
    for (int i = 0; i < 16; ++i) {
        int idx = i * 256 + t;
        int rr = idx >> 6, cc = idx & 63;
        int n = n0 + rr;
        int p = n;
        if (permN) {
            p = (n < permN) ? (((n >> 4) << 5) + (n & 15))
                            : ((((n - permN) >> 4) << 5) + 16 + ((n - permN) & 15));
        }
        d[(size_t)p * K + k0 + cc] = f2b(tile[cc][rr]);
    }
}

__global__ __launch_bounds__(256) void conv_f2b(const float* __restrict__ in,
                                                u16* __restrict__ out)
{
    size_t i = (size_t)blockIdx.x * 256 + threadIdx.x;
    float4 v = ((const float4*)in)[i];
    u16x4 o;
    o[0] = f2b(v.x); o[1] = f2b(v.y); o[2] = f2b(v.z); o[3] = f2b(v.w);
    ((u16x4*)out)[i] = o;
}

// ---------------------------------------------------------------------------
__global__ __launch_bounds__(512) void bn_colstats(const float* __restrict__ x,
                                                   float* __restrict__ cs,
                                                   float* __restrict__ cq)
{
    int c = threadIdx.x;
    int r0 = blockIdx.x * 128;
    float s = 0.f, q = 0.f;
    for (int r = 0; r < 128; ++r) {
        float v = x[(size_t)(r0 + r) * DIM + c];
        s += v; q += v * v;
    }
    atomicAdd(&cs[c], s);
    atomicAdd(&cq[c], q);
}

__global__ void bn_finalize(const float* __restrict__ cs, const float* __restrict__ cq,
                            const float* __restrict__ bw, const float* __restrict__ bb,
                            float* __restrict__ scale, float* __restrict__ shift)
{
    int c = threadIdx.x;
    float m   = cs[c] * (1.f / N_NODES);
    float var = cq[c] * (1.f / N_NODES) - m * m;
    float rs  = rsqrtf(var + LNEPS);
    float sc  = rs * bw[c];
    scale[c] = sc;
    shift[c] = bb[c] - m * sc;
}

__global__ __launch_bounds__(256) void bn_apply_b(const float* __restrict__ x,
                                                  const float* __restrict__ scale,
                                                  const float* __restrict__ shift,
                                                  u16* __restrict__ out)
{
    size_t idx = (size_t)blockIdx.x * 256 + threadIdx.x;
    int c4 = (int)(idx & 127);
    float4 v  = ((const float4*)x)[idx];
    float4 sc = ((const float4*)scale)[c4];
    float4 sh = ((const float4*)shift)[c4];
    u16x4 o;
    o[0] = f2b(v.x * sc.x + sh.x); o[1] = f2b(v.y * sc.y + sh.y);
    o[2] = f2b(v.z * sc.z + sh.z); o[3] = f2b(v.w * sc.w + sh.w);
    ((u16x4*)out)[idx] = o;
}

__global__ __launch_bounds__(256) void layernorm_b(const float* __restrict__ in,
                                                   const float* __restrict__ w,
                                                   const float* __restrict__ bsh,
                                                   u16* __restrict__ out)
{
    int lane = threadIdx.x & 63, wv = threadIdx.x >> 6;
    size_t row = (size_t)blockIdx.x * 4 + wv;
    const float* p = in + row * DIM + lane * 8;
    float4 v0 = *(const float4*)p;
    float4 v1 = *(const float4*)(p + 4);
    float s = v0.x + v0.y + v0.z + v0.w + v1.x + v1.y + v1.z + v1.w;
    float q = v0.x * v0.x + v0.y * v0.y + v0.z * v0.z + v0.w * v0.w +
              v1.x * v1.x + v1.y * v1.y + v1.z * v1.z + v1.w * v1.w;
    for (int m = 1; m < 64; m <<= 1) {
        s += __shfl_xor(s, m, 64);
        q += __shfl_xor(q, m, 64);
    }
    float mean = s * (1.f / DIM);
    float rs = rsqrtf(q * (1.f / DIM) - mean * mean + LNEPS);
    float4 w0 = *(const float4*)(w + lane * 8),   w1 = *(const float4*)(w + lane * 8 + 4);
    float4 b0 = *(const float4*)(bsh + lane * 8), b1 = *(const float4*)(bsh + lane * 8 + 4);
    u16x8 o;
    o[0] = f2b((v0.x - mean) * rs * w0.x + b0.x);
    o[1] = f2b((v0.y - mean) * rs * w0.y + b0.y);
    o[2] = f2b((v0.z - mean) * rs * w0.z + b0.z);
    o[3] = f2b((v0.w - mean) * rs * w0.w + b0.w);
    o[4] = f2b((v1.x - mean) * rs * w1.x + b1.x);
    o[5] = f2b((v1.y - mean) * rs * w1.y + b1.y);
    o[6] = f2b((v1.z - mean) * rs * w1.z + b1.z);
    o[7] = f2b((v1.w - mean) * rs * w1.w + b1.w);
    *(u16x8*)(out + row * DIM + lane * 8) = o;
}

// ---------------------------------------------------------------------------
// Fused attention (MCTX fits LDS). Per block: 256 q-rows, one (head, batch).
// ---------------------------------------------------------------------------
__global__ __launch_bounds__(256) void fused_attn(
    const u16* __restrict__ Q,    // [16384][512]
    const u16* __restrict__ Kp,   // [4096][512]
    const u16* __restrict__ Vt,   // [16][8][64][256]
    u16* __restrict__ O)          // [16384][512]
{
    __shared__ u16 Ks[256 * 64];
    __shared__ u16 Vs[64 * 256];
    __shared__ u16 Ps[4][16 * 256];

    const int t = threadIdx.x;
    const int wave = t >> 6, lane = t & 63;
    const int fr = lane & 15, fq = lane >> 4;
    const int qc = blockIdx.x, h = blockIdx.y, b = blockIdx.z;
    const int ldsW = (t & 192) * 16;

#pragma unroll
    for (int i = 0; i < 8; ++i) {
        int idx = i * 256 + t;
        int m = idx >> 3, s = idx & 7;
        gload16(Kp + (size_t)(b * MCTX + m) * 512 + h * 64 + ((s ^ (m & 7)) * 8),
                (char*)Ks + i * 4096 + ldsW);
    }
#pragma unroll
    for (int i = 0; i < 8; ++i) {
        int idx = i * 256 + t;
        int d = idx >> 5, s = idx & 31;
        gload16(Vt + (size_t)((b * 8 + h) * 64 + d) * 256 + ((s ^ (d & 7)) * 8),
                (char*)Vs + i * 4096 + ldsW);
    }
    __syncthreads();

    u16* Pw = Ps[wave];
    for (int it = 0; it < 4; ++it) {
        const int q0 = qc * 256 + it * 64 + wave * 16;
        bf16x8 aq[2];
#pragma unroll
        for (int ks = 0; ks < 2; ++ks)
            aq[ks] = *(const bf16x8*)&Q[(size_t)(b * SEQ + q0 + fr) * 512 +
                                        h * 64 + ks * 32 + fq * 8];
        f32x4 accS[16];
#pragma unroll
        for (int ni = 0; ni < 16; ++ni) accS[ni] = (f32x4){0.f, 0.f, 0.f, 0.f};
#pragma unroll
        for (int ni = 0; ni < 16; ++ni) {
            int m = ni * 16 + fr;
#pragma unroll
            for (int ks = 0; ks < 2; ++ks) {
                bf16x8 bv = *(const bf16x8*)&Ks[m * 64 + (((ks * 4 + fq) ^ (m & 7)) * 8)];
                accS[ni] = __builtin_amdgcn_mfma_f32_16x16x32_bf16(
                    aq[ks], bv, accS[ni], 0, 0, 0);
            }
        }
        const float cs = 0.125f;
#pragma unroll
        for (int j = 0; j < 4; ++j) {
            float m0 = accS[0][j];
#pragma unroll
            for (int ni = 1; ni < 16; ++ni) m0 = fmaxf(m0, accS[ni][j]);
            m0 = fmaxf(m0, __shfl_xor(m0, 1, 64));
            m0 = fmaxf(m0, __shfl_xor(m0, 2, 64));
            m0 = fmaxf(m0, __shfl_xor(m0, 4, 64));
            m0 = fmaxf(m0, __shfl_xor(m0, 8, 64));
            float s0 = 0.f;
#pragma unroll
            for (int ni = 0; ni < 16; ++ni) {
                float p = __expf((accS[ni][j] - m0) * cs);
                accS[ni][j] = p;
                s0 += p;
            }
            s0 += __shfl_xor(s0, 1, 64);
            s0 += __shfl_xor(s0, 2, 64);
            s0 += __shfl_xor(s0, 4, 64);
            s0 += __shfl_xor(s0, 8, 64);
            float inv = 1.f / s0;
#pragma unroll
            for (int ni = 0; ni < 16; ++ni) {
                int cc = ni * 16 + fr;
                int rr = fq * 4 + j;
                Pw[rr * 256 + (((cc >> 3) ^ (rr & 7)) * 8) + (cc & 7)] =
                    f2b(accS[ni][j] * inv);
            }
        }
        bf16x8 ap[8];
#pragma unroll
        for (int ks = 0; ks < 8; ++ks)
            ap[ks] = *(const bf16x8*)&Pw[fr * 256 + (((ks * 4 + fq) ^ (fr & 7)) * 8)];
        f32x4 accO[4];
#pragma unroll
        for (int ni = 0; ni < 4; ++ni) accO[ni] = (f32x4){0.f, 0.f, 0.f, 0.f};
#pragma unroll
        for (int ni = 0; ni < 4; ++ni) {
            int d = ni * 16 + fr;
#pragma unroll
            for (int ks = 0; ks < 8; ++ks) {
                bf16x8 bv = *(const bf16x8*)&Vs[d * 256 + (((ks * 4 + fq) ^ (d & 7)) * 8)];
                accO[ni] = __builtin_amdgcn_mfma_f32_16x16x32_bf16(
                    ap[ks], bv, accO[ni], 0, 0, 0);
            }
        }
#pragma unroll
        for (int ni = 0; ni < 4; ++ni)
#pragma unroll
            for (int j = 0; j < 4; ++j)
                O[(size_t)(b * SEQ + q0 + fq * 4 + j) * 512 + h * 64 + ni * 16 + fr] =
                    f2b(accO[ni][j]);
    }
}

// ---------------------------------------------------------------------------
__global__ void detect_i64(const int* __restrict__ e, int* __restrict__ flag)
{
    int idx = blockIdx.x * blockDim.x + threadIdx.x;
    if (e[2 * idx + 1] != 0) flag[0] = 1;
}

__global__ void deg_count(const int* __restrict__ eb, const int* __restrict__ flag,
                          int* __restrict__ deg)
{
    int e = blockIdx.x * blockDim.x + threadIdx.x;
    int d;
    if (flag[0]) d = eb[NEDGE + e];
    else         d = (int)((const long long*)eb)[NEDGE + e];
    atomicAdd(&deg[d], 1);
}

__global__ void dinv_k(const int* __restrict__ deg, float* __restrict__ dinv)
{
    int i = blockIdx.x * blockDim.x + threadIdx.x;
    dinv[i] = rsqrtf((float)(deg[i] + 1));
}

__global__ __launch_bounds__(1024) void scan_deg(const int* __restrict__ deg,
                                                 int* __restrict__ off)
{
    __shared__ int sums[1024];
    int t = threadIdx.x;
    int base = t * 16;
    int v[16]; int s = 0;
#pragma unroll
    for (int i = 0; i < 16; ++i) { v[i] = deg[base + i]; s += v[i]; }
    sums[t] = s;
    __syncthreads();
    for (int ofs = 1; ofs < 1024; ofs <<= 1) {
        int x = (t >= ofs) ? sums[t - ofs] : 0;
        __syncthreads();
        sums[t] += x;
        __syncthreads();
    }
    int run = (t == 0) ? 0 : sums[t - 1];
#pragma unroll
    for (int i = 0; i < 16; ++i) { off[base + i] = run; run += v[i]; }
    if (t == 1023) off[N_NODES] = run;
}

__global__ void fill_k(const int* __restrict__ eb, const int* __restrict__ flag,
                       const int* __restrict__ off, int* __restrict__ cursor,
                       int* __restrict__ csr)
{
    int e = blockIdx.x * blockDim.x + threadIdx.x;
    int s, d;
    if (flag[0]) { s = eb[e]; d = eb[NEDGE + e]; }
    else {
        const long long* p = (const long long*)eb;
        s = (int)p[e]; d = (int)p[NEDGE + e];
    }
    int pos = atomicAdd(&cursor[d], 1);
    csr[off[d] + pos] = s;
}

// h2 rows are PRE-SCALED by dinv[row]; 2-way unrolled independent row loads.
__global__ __launch_bounds__(256) void gcn_gather(
    const u16* __restrict__ h2, const int* __restrict__ csr,
    const int* __restrict__ off, const float* __restrict__ dinv,
    const float* __restrict__ bias, const float* __restrict__ addx,
    float* __restrict__ out)
{
    int lane = threadIdx.x & 63, wv = threadIdx.x >> 6;
    int d = blockIdx.x * 4 + wv;
    float a0[8], a1[8];
#pragma unroll
    for (int j = 0; j < 8; ++j) { a0[j] = 0.f; a1[j] = 0.f; }
    int e0 = off[d], e1 = off[d + 1];
    float dd = dinv[d];
    int e = e0;
    if ((e1 - e0) & 1) {
        u16x8 v = *(const u16x8*)&h2[(size_t)csr[e] * DIM + lane * 8];
#pragma unroll
        for (int j = 0; j < 8; ++j) a0[j] += b2f(v[j]);
        ++e;
    }
    for (; e < e1; e += 2) {
        int s0 = csr[e], s1 = csr[e + 1];
        u16x8 v0 = *(const u16x8*)&h2[(size_t)s0 * DIM + lane * 8];
        u16x8 v1 = *(const u16x8*)&h2[(size_t)s1 * DIM + lane * 8];
#pragma unroll
        for (int j = 0; j < 8; ++j) a0[j] += b2f(v0[j]);
#pragma unroll
        for (int j = 0; j < 8; ++j) a1[j] += b2f(v1[j]);
    }
    u16x8 vd = *(const u16x8*)&h2[(size_t)d * DIM + lane * 8];
    float o[8];
#pragma unroll
    for (int j = 0; j < 8; ++j) {
        o[j] = (a0[j] + a1[j] + b2f(vd[j])) * dd + bias[lane * 8 + j];
        if (addx) o[j] += addx[(size_t)d * DIM + lane * 8 + j];
    }
    float* op = out + (size_t)d * DIM + lane * 8;
    *(float4*)op = make_float4(o[0], o[1], o[2], o[3]);
    *(float4*)(op + 4) = make_float4(o[4], o[5], o[6], o[7]);
}

// ---------------------------------------------------------------------------
extern "C" void kernel_launch(void* const* d_in, const int* in_sizes, int n_in,
                              void* d_out, int out_size, void* d_ws, size_t ws_size,
                              hipStream_t stream)
{
    const float* x         = (const float*)d_in[0];
    const int*   edges     = (const int*)d_in[1];
    const float* cond      = (const float*)d_in[2];
    const float* bn_w      = (const float*)d_in[3];
    const float* bn_b      = (const float*)d_in[4];
    const float* gcn_in_w  = (const float*)d_in[5];
    const float* gcn_in_b  = (const float*)d_in[6];
    const float* gcn_out_w = (const float*)d_in[7];
    const float* gcn_out_b = (const float*)d_in[8];
    const float* Wq  = (const float*)d_in[9];
    const float* Wk  = (const float*)d_in[10];
    const float* Wv  = (const float*)d_in[11];
    const float* Wo  = (const float*)d_in[12];
    const float* ln2w = (const float*)d_in[13];
    const float* ln2b = (const float*)d_in[14];
    const float* ln3w = (const float*)d_in[15];
    const float* ln3b = (const float*)d_in[16];
    const float* ggw = (const float*)d_in[17];
    const float* ggb = (const float*)d_in[18];
    const float* fow = (const float*)d_in[19];
    const float* fob = (const float*)d_in[20];
    float* outp = (float*)d_out;

    char* wsb = (char*)d_ws;
    size_t wsoff = 0;
    auto alloc = [&](size_t bytes) -> void* {
        void* p = wsb + wsoff;
        wsoff = (wsoff + bytes + 255) & ~(size_t)255;
        return p;
    };
    u16*   wT    = (u16*)  alloc((size_t)17301504 * 2);
    u16*   condb = (u16*)  alloc((size_t)4096 * 512 * 2);
    float* h     = (float*)alloc((size_t)N_NODES * DIM * 4);
    u16*   t0b   = (u16*)  alloc((size_t)N_NODES * DIM * 2);
    u16*   qb    = (u16*)  alloc((size_t)N_NODES * DIM * 2);
    u16*   ob    = (u16*)  alloc((size_t)N_NODES * DIM * 2);
    u16*   kb    = (u16*)  alloc((size_t)NLAYER * 4096 * 512 * 2);          // all layers
    u16*   Vt    = (u16*)  alloc((size_t)NLAYER * BSZ * NHEAD * DHEAD * MCTX * 2);
    char*  zbase  = wsb + wsoff;
    float* colsum = (float*)alloc(DIM * 4);
    float* colsq  = (float*)alloc(DIM * 4);
    int*   deg    = (int*)  alloc(N_NODES * 4);
    int*   cursor = (int*)  alloc(N_NODES * 4);
    int*   eflag  = (int*)  alloc(256);
    size_t zbytes = (size_t)((wsb + wsoff) - zbase);
    float* bscale = (float*)alloc(DIM * 4);
    float* bshift = (float*)alloc(DIM * 4);
    float* dinv   = (float*)alloc(N_NODES * 4);
    int*   csr_off= (int*)  alloc((N_NODES + 16) * 4);
    int*   csr_src= (int*)  alloc((size_t)NEDGE * 4);

    // FFN chunking: Ab [rows][2048] bf16 ; rows stay multiple of 256
    int nch = 0;
    for (int c = 1; c <= 16; c *= 2) {
        size_t need = ((size_t)N_NODES / c) * DFF * 2;
        if (wsoff + need <= ws_size) { nch = c; break; }
    }
    if (nch == 0) { fprintf(stderr, "ws too small (%zu)\n", ws_size); return; }
    u16* Abuf = (u16*)(wsb + wsoff);

    hipMemsetAsync(zbase, 0, zbytes, stream);

    // weight transposes (batched over layers); gg uses frag-pair perm
    u16* gcnInT  = wT;
    u16* gcnOutT = gcnInT + 262144;
    u16* WqT = gcnOutT + 262144;
    u16* WkT = WqT + 4 * 262144;
    u16* WvT = WkT + 4 * 262144;
    u16* WoT = WvT + 4 * 262144;
    u16* ggT = WoT + 4 * 262144;
    u16* foT = ggT + 4 * 2097152;
    transposeW<<<dim3(8, 8, 1), 256, 0, stream>>>(gcn_in_w,  gcnInT, 512, 512, 0, 0, 0);
    transposeW<<<dim3(8, 8, 1), 256, 0, stream>>>(gcn_out_w, gcnOutT, 512, 512, 0, 0, 0);
    transposeW<<<dim3(8, 8, 4), 256, 0, stream>>>(Wq, WqT, 512, 512, 262144, 262144, 0);
    transposeW<<<dim3(8, 8, 4), 256, 0, stream>>>(Wk, WkT, 512, 512, 262144, 262144, 0);
    transposeW<<<dim3(8, 8, 4), 256, 0, stream>>>(Wv, WvT, 512, 512, 262144, 262144, 0);
    transposeW<<<dim3(8, 8, 4), 256, 0, stream>>>(Wo, WoT, 512, 512, 262144, 262144, 0);
    transposeW<<<dim3(64, 8, 4), 256, 0, stream>>>(ggw, ggT, 512, DG, 2097152, 2097152, DFF);
    transposeW<<<dim3(8, 32, 4), 256, 0, stream>>>(fow, foT, DFF, 512, 1048576, 1048576, 0);
    conv_f2b<<<2048, 256, 0, stream>>>(cond, condb);

    // BatchNorm
    bn_colstats<<<128, 512, 0, stream>>>(x, colsum, colsq);
    bn_finalize<<<1, 512, 0, stream>>>(colsum, colsq, bn_w, bn_b, bscale, bshift);
    bn_apply_b<<<(N_NODES * DIM / 4) / 256, 256, 0, stream>>>(x, bscale, bshift, t0b);

    // graph prep
    detect_i64<<<NEDGE / 256, 256, 0, stream>>>(edges, eflag);
    deg_count<<<NEDGE / 256, 256, 0, stream>>>(edges, eflag, deg);
    dinv_k<<<N_NODES / 256, 256, 0, stream>>>(deg, dinv);
    scan_deg<<<1, 1024, 0, stream>>>(deg, csr_off);
    fill_k<<<NEDGE / 256, 256, 0, stream>>>(edges, eflag, csr_off, cursor, csr_src);

    // K/V projections for ALL layers (cond is layer-invariant), batched z=4
    bgemm<1><<<dim3(4, 32, 4), 256, 0, stream>>>(
        condb, 512, WkT, 512, nullptr, nullptr, 0, nullptr, kb, 512, 512, 1,
        0, 0, 262144, 0, (long)4096 * 512, 0);
    bgemm<3><<<dim3(4, 32, 4), 256, 0, stream>>>(
        condb, 512, WvT, 512, nullptr, nullptr, 0, nullptr, Vt, 0, 512, 1,
        0, 0, 262144, 0, (long)BSZ * NHEAD * DHEAD * MCTX, 0);

    // GCN in (rows pre-scaled by dinv via EPI=4)
    bgemm<4><<<dim3(4, 128, 1), 256, 0, stream>>>(
        t0b, 512, gcnInT, 512, nullptr, nullptr, 0, dinv, qb, 512, 512, 1,
        0, 0, 0, 0, 0, 0);
    gcn_gather<<<N_NODES / 4, 256, 0, stream>>>(qb, csr_src, csr_off, dinv,
                                                gcn_in_b, nullptr, h);

    const int ffrows = N_NODES / nch;
    for (int i = 0; i < NLAYER; ++i) {
        const u16* WqTi = WqT + (size_t)i * 262144;
        const u16* WoTi = WoT + (size_t)i * 262144;
        const u16* ggTi = ggT + (size_t)i * 2097152;
        const u16* foTi = foT + (size_t)i * 1048576;
        const u16* kbi  = kb + (size_t)i * 4096 * 512;
        const u16* Vti  = Vt + (size_t)i * BSZ * NHEAD * DHEAD * MCTX;

        // attention
        layernorm_b<<<N_NODES / 4, 256, 0, stream>>>(h, ln2w + i * DIM, ln2b + i * DIM, t0b);
        bgemm<1><<<dim3(4, 128, 1), 256, 0, stream>>>(
            t0b, 512, WqTi, 512, nullptr, nullptr, 0, nullptr, qb, 512, 512, 1,
            0, 0, 0, 0, 0, 0);
        fused_attn<<<dim3(4, 8, 16), 256, 0, stream>>>(qb, kbi, Vti, ob);
        bgemm<2><<<dim3(4, 128, 1), 256, 0, stream>>>(
            ob, 512, WoTi, 512, nullptr, h, 512, nullptr, h, 512, 512, 1,
            0, 0, 0, 0, 0, 0);

        // GEGLU FFN: 256^2 2-fat-phase GEMM with fused pair-in-thread act
        layernorm_b<<<N_NODES / 4, 256, 0, stream>>>(h, ln3w + i * DIM, ln3b + i * DIM, t0b);
        for (int c = 0; c < nch; ++c) {
            const u16* ac = t0b + (size_t)c * ffrows * 512;
            float* hc = h + (size_t)c * ffrows * 512;
            bgemm256_geglu<<<dim3(DG / 256, ffrows / 256), 512, 0, stream>>>(
                ac, 512, ggTi, 512, ggb + (size_t)i * DG, Abuf, 512);
            bgemm<2><<<dim3(4, ffrows / 128, 1), 256, 0, stream>>>(
                Abuf, 2048, foTi, 2048, fob + (size_t)i * DIM, hc, 512, nullptr,
                hc, 512, 2048, 1, 0, 0, 0, 0, 0, 0);
        }
    }

    // GCN out + residual x
    conv_f2b<<<8192, 256, 0, stream>>>(h, t0b);
    bgemm<4><<<dim3(4, 128, 1), 256, 0, stream>>>(
        t0b, 512, gcnOutT, 512, nullptr, nullptr, 0, dinv, qb, 512, 512, 1,
        0, 0, 0, 0, 0, 0);
    gcn_gather<<<N_NODES / 4, 256, 0, stream>>>(qb, csr_src, csr_off, dinv,
                                                gcn_out_b, x, outp);
}

// Round 8
// 1172.566 us; speedup vs baseline: 1.0589x; 1.0589x over previous
//
#include <hip/hip_runtime.h>
#include <math.h>
#include <stdio.h>

#define N_NODES 16384
#define DIM     512
#define BSZ     16
#define SEQ     1024
#define MCTX    256
#define NHEAD   8
#define DHEAD   64
#define NLAYER  4
#define NEDGE   262144
#define DFF     2048
#define DG      4096
#define LNEPS   1e-5f

typedef unsigned short u16;
typedef __attribute__((ext_vector_type(8))) __bf16 bf16x8;
typedef __attribute__((ext_vector_type(4))) float f32x4;
typedef __attribute__((ext_vector_type(4))) unsigned short u16x4;
typedef __attribute__((ext_vector_type(8))) unsigned short u16x8;

__device__ __forceinline__ u16 f2b(float f) {
    unsigned u = __float_as_uint(f);
    unsigned r = (u + 0x7fff + ((u >> 16) & 1)) >> 16;
    return (u16)r;
}
__device__ __forceinline__ float b2f(u16 h) {
    return __uint_as_float((unsigned)h << 16);
}
__device__ __forceinline__ float gelu_exact(float x) {
    return 0.5f * x * (1.0f + erff(x * 0.70710678118654752f));
}
// tanh-approx gelu via hardware exp; |err| vs exact < 2e-3
__device__ __forceinline__ float gelu_fast(float x) {
    float u = x * (0.7978845608f + 0.0356774081f * x * x);
    float e = __expf(2.f * u);
    float t = 1.f - 2.f / (e + 1.f);
    return 0.5f * x * (1.f + t);
}
__device__ __forceinline__ void gload16(const void* g, void* l) {
    __builtin_amdgcn_global_load_lds(
        (const __attribute__((address_space(1))) unsigned int*)g,
        (__attribute__((address_space(3))) unsigned int*)l, 16, 0, 0);
}

// bijective XCD-chunk swizzle (m204)
__device__ __forceinline__ int2 xcd_map() {
    int gx = gridDim.x, gy = gridDim.y;
    int nwg = gx * gy;
    int id = blockIdx.y * gx + blockIdx.x;
    int q = nwg >> 3, r = nwg & 7;
    int xcd = id & 7, idx = id >> 3;
    int nid = (xcd < r ? xcd * (q + 1) : r * (q + 1) + (xcd - r) * q) + idx;
    int2 o; o.x = nid % gx; o.y = nid / gx; return o;
}

// ---------------------------------------------------------------------------
// 256x256 bf16 GEMM, K=512 (NT=8 FULLY UNROLLED: compile-time buffers/guards
// -> loop-invariant swizzled LDS addresses, no per-tile VALU addr recompute).
// Per tile: phase X {read A-P0 + all B, stage kt+1-h2, 32 MFMA},
//           phase Y {read A-P1, stage kt+2-h1, 32 MFMA, vmcnt(4)}.
// Fused GEGLU epilogue (pair-interleaved W), padded LDS bounce (stride 40).
// ---------------------------------------------------------------------------
__global__ __launch_bounds__(512, 2) void bgemm256_geglu(
    const u16* __restrict__ A, long lda,
    const u16* __restrict__ Bt, long ldb,
    const float* __restrict__ bias,
    u16* __restrict__ Cb, int K)
{
    __shared__ u16 lds[65536];   // A0 A1 B0 B1, 32KB each (u16 offsets 16384)

    const int t = threadIdx.x;
    const int w = t >> 6, lane = t & 63;
    const int fr = lane & 15, fq = lane >> 4;
    int2 sw = xcd_map();
    const int row0 = sw.y * 256;
    const int col0 = sw.x * 256;
    const int wm0 = (w >> 2) * 128, wn0 = (w & 3) * 64;
    const int sl = (lane & 7) ^ ((lane >> 3) & 7);   // src slot for staging

    f32x4 acc[8][4];
#pragma unroll
    for (int mf = 0; mf < 8; ++mf)
#pragma unroll
        for (int nf = 0; nf < 4; ++nf) acc[mf][nf] = (f32x4){0.f, 0.f, 0.f, 0.f};

    auto stageA = [&](int kt_, int P, int bb) {
        const int k0 = kt_ << 6;
#pragma unroll
        for (int rd = 0; rd < 2; ++rd) {
            int rbase = rd * 128 + P * 64 + w * 8;            // wave-uniform
            int r = rbase + (lane >> 3);
            gload16(A + (size_t)(row0 + r) * lda + k0 + sl * 8,
                    (char*)(lds + bb * 16384) + rbase * 128);
        }
    };
    auto stageB = [&](int kt_, int Q, int bb) {
        const int k0 = kt_ << 6;
#pragma unroll
        for (int rd = 0; rd < 2; ++rd) {
            int jb = rd * 64 + w * 8;
            int nbase = ((jb >> 5) << 6) + Q * 32 + (jb & 31); // wave-uniform
            int n = nbase + (lane >> 3);
            gload16(Bt + (size_t)(col0 + n) * ldb + k0 + sl * 8,
                    (char*)(lds + 32768 + bb * 16384) + nbase * 128);
        }
    };

#define READ_A(MH, DST) do {                                                   \
    _Pragma("unroll")                                                          \
    for (int mi = 0; mi < 4; ++mi) {                                           \
        int r = wm0 + (MH) * 64 + mi * 16 + fr;                                \
        _Pragma("unroll")                                                      \
        for (int ks = 0; ks < 2; ++ks)                                         \
            DST[mi][ks] = *(const bf16x8*)&Ab_[r * 64 + (((ks*4+fq) ^ (fr&7)) * 8)]; \
    } } while (0)
#define READ_B_ALL(DST) do {                                                   \
    _Pragma("unroll")                                                          \
    for (int ni = 0; ni < 4; ++ni) {                                           \
        int n = wn0 + ni * 16 + fr;                                            \
        _Pragma("unroll")                                                      \
        for (int ks = 0; ks < 2; ++ks)                                         \
            DST[ni][ks] = *(const bf16x8*)&Bb_[n * 64 + (((ks*4+fq) ^ (fr&7)) * 8)]; \
    } } while (0)
#define MFMA32(MH, AV, BV)                                                     \
    _Pragma("unroll")                                                          \
    for (int mi = 0; mi < 4; ++mi)                                             \
        _Pragma("unroll")                                                      \
        for (int ni = 0; ni < 4; ++ni)                                         \
            _Pragma("unroll")                                                  \
            for (int ks = 0; ks < 2; ++ks)                                     \
                acc[(MH)*4+mi][ni] = __builtin_amdgcn_mfma_f32_16x16x32_bf16(  \
                    AV[mi][ks], BV[ni][ks], acc[(MH)*4+mi][ni], 0, 0, 0)

    // prologue: tile0 all regions (8 loads) + tile1 half1 (A-P0,B-Q0: 4 loads)
    stageA(0, 0, 0); stageB(0, 0, 0); stageA(0, 1, 0); stageB(0, 1, 0);
    stageA(1, 0, 1); stageB(1, 0, 1);
    asm volatile("s_waitcnt vmcnt(4)" ::: "memory");
    __builtin_amdgcn_s_barrier();

#pragma unroll
    for (int kt = 0; kt < 8; ++kt) {          // NT = 8 compile-time
        const int b = kt & 1;
        const bool s1 = (kt + 1 < 8), s2 = (kt + 2 < 8);
        const u16* Ab_ = lds + b * 16384;
        const u16* Bb_ = lds + 32768 + b * 16384;
        bf16x8 av[4][2], bv[4][2];

        // phase X: A-P0 + all B; stage kt+1 half2 into b^1
        READ_A(0, av); READ_B_ALL(bv);
        if (s1) { stageA(kt + 1, 1, b ^ 1); stageB(kt + 1, 1, b ^ 1); }
        __builtin_amdgcn_s_barrier();
        asm volatile("s_waitcnt lgkmcnt(0)" ::: "memory");
        __builtin_amdgcn_s_setprio(1);
        MFMA32(0, av, bv);
        __builtin_amdgcn_s_setprio(0);
        __builtin_amdgcn_s_barrier();

        // phase Y: A-P1 (disjoint from kt+2's A-P0 staging); B reg-carried
        READ_A(1, av);
        if (s2) { stageA(kt + 2, 0, b); stageB(kt + 2, 0, b); }
        __builtin_amdgcn_s_barrier();
        asm volatile("s_waitcnt lgkmcnt(0)" ::: "memory");
        __builtin_amdgcn_s_setprio(1);
        MFMA32(1, av, bv);
        __builtin_amdgcn_s_setprio(0);
        if (s2)      asm volatile("s_waitcnt vmcnt(4)" ::: "memory");
        else if (s1) asm volatile("s_waitcnt vmcnt(0)" ::: "memory");
        __builtin_amdgcn_s_barrier();
    }
#undef READ_A
#undef READ_B_ALL
#undef MFMA32

    // fused GEGLU epilogue: acc[mf][2P]=val frag, acc[mf][2P+1]=gate frag.
    // Per-wave LDS bounce (PADDED stride 40 u16 -> 2-way max bank aliasing),
    // then block-cooperative coalesced stores.
    const int nbase = (col0 + wn0) >> 1;
    float bval[2], bgat[2];
#pragma unroll
    for (int P = 0; P < 2; ++P) {
        int n = nbase + P * 16 + fr;
        bval[P] = bias[n];
        bgat[P] = bias[DFF + n];
    }
    {
        u16* Tw = lds + w * 5120;   // wave tile: 128 rows x 32 cols, stride 40
#pragma unroll
        for (int mf = 0; mf < 8; ++mf)
#pragma unroll
            for (int P = 0; P < 2; ++P)
#pragma unroll
                for (int j = 0; j < 4; ++j) {
                    float v = acc[mf][2 * P][j] + bval[P];
                    float g = acc[mf][2 * P + 1][j] + bgat[P];
                    Tw[(mf * 16 + fq * 4 + j) * 40 + P * 16 + fr] =
                        f2b(v * gelu_fast(g));
                }
    }
    __syncthreads();
    const long cb0 = col0 >> 1;
#pragma unroll
    for (int i = 0; i < 8; ++i) {
        int chunk = i * 512 + t;           // 0..4095
        int r = chunk >> 4;                // 0..255
        int c8 = (chunk & 15) * 8;         // 0..120
        int sw_ = (r >> 7) * 4 + (c8 >> 5);
        u16x8 v = *(const u16x8*)&lds[sw_ * 5120 + (r & 127) * 40 + (c8 & 31)];
        *(u16x8*)&Cb[(size_t)(row0 + r) * DFF + cb0 + c8] = v;
    }
}

// ---------------------------------------------------------------------------
// bf16 MFMA GEMM, 128x128 tile, BK=64, double-buffered LDS, XCD swizzle.
// EPI: 1 = bf16 out (+bias) ; 2 = f32 out = acc+bias+resid ;
//      3 = V-transpose (LDS bounce -> Vt[z][b][h][d][m]) ; 4 = bf16 rowscale
// ---------------------------------------------------------------------------
template<int EPI>
__global__ __launch_bounds__(256) void bgemm(
    const u16* __restrict__ A, long lda,
    const u16* __restrict__ Bt, long ldb,
    const float* __restrict__ bias,
    const float* __restrict__ resid, long ldr,
    const float* __restrict__ rowscale,
    void* __restrict__ Cv, long ldc, int K, int nlo,
    long aHi, long aLo, long bHi, long bLo, long cHi, long cLo)
{
    __shared__ u16 lds[32768];    // A0 | A1 | B0 | B1, 16KB each

    const int t = threadIdx.x;
    const int z = blockIdx.z;
    const int zhi = z / nlo, zlo = z % nlo;
    const u16* Ag = A + (size_t)zhi * aHi + (size_t)zlo * aLo;
    const u16* Bg = Bt + (size_t)zhi * bHi + (size_t)zlo * bLo;
    const long coff = (long)zhi * cHi + (long)zlo * cLo;

    int2 sw = xcd_map();
    const int row0 = sw.y * 128;
    const int col0 = sw.x * 128;
    const int wave = t >> 6, lane = t & 63;
    const int wm0 = (wave >> 1) * 64, wn0 = (wave & 1) * 64;
    const int fr = lane & 15, fq = lane >> 4;
    const int ldsWave = (t & 192) * 16;
    const int rS = t >> 3;
    const int slotP = t & 7;

    f32x4 acc[4][4];
#pragma unroll
    for (int mi = 0; mi < 4; ++mi)
#pragma unroll
        for (int ni = 0; ni < 4; ++ni) acc[mi][ni] = (f32x4){0.f, 0.f, 0.f, 0.f};

    auto stage = [&](int buf, int k0) {
        u16* Ad = lds + buf * 8192;
        u16* Bd = lds + 16384 + buf * 8192;
#pragma unroll
        for (int i = 0; i < 4; ++i) {
            int r = i * 32 + rS;
            int s2 = slotP ^ (r & 7);
            gload16(Ag + (size_t)(row0 + r) * lda + k0 + s2 * 8,
                    (char*)Ad + i * 4096 + ldsWave);
        }
#pragma unroll
        for (int i = 0; i < 4; ++i) {
            int r = i * 32 + rS;
            int s2 = slotP ^ (r & 7);
            gload16(Bg + (size_t)(col0 + r) * ldb + k0 + s2 * 8,
                    (char*)Bd + i * 4096 + ldsWave);
        }
    };
    auto compute = [&](int buf) {
        const u16* Ac = lds + buf * 8192;
        const u16* Bc = lds + 16384 + buf * 8192;
#pragma unroll
        for (int ks = 0; ks < 2; ++ks) {
            const int ksl = ks * 4 + fq;
            bf16x8 av[4], bv[4];
#pragma unroll
            for (int mi = 0; mi < 4; ++mi) {
                int r = wm0 + mi * 16 + fr;
                av[mi] = *(const bf16x8*)&Ac[r * 64 + ((ksl ^ (r & 7)) * 8)];
            }
#pragma unroll
            for (int ni = 0; ni < 4; ++ni) {
                int r = wn0 + ni * 16 + fr;
                bv[ni] = *(const bf16x8*)&Bc[r * 64 + ((ksl ^ (r & 7)) * 8)];
            }
#pragma unroll
            for (int mi = 0; mi < 4; ++mi)
#pragma unroll
                for (int ni = 0; ni < 4; ++ni)
                    acc[mi][ni] = __builtin_amdgcn_mfma_f32_16x16x32_bf16(
                        av[mi], bv[ni], acc[mi][ni], 0, 0, 0);
        }
    };

    int cur = 0;
    stage(0, 0);
    __syncthreads();
    for (int k0 = 64; k0 < K; k0 += 64) {
        stage(cur ^ 1, k0);
        compute(cur);
        __syncthreads();
        cur ^= 1;
    }
    compute(cur);

    if (EPI == 3) {
        __syncthreads();
        u16* Tw = lds + wave * 4608;   // 64 x 72
#pragma unroll
        for (int mi = 0; mi < 4; ++mi)
#pragma unroll
            for (int ni = 0; ni < 4; ++ni)
#pragma unroll
                for (int j = 0; j < 4; ++j)
                    Tw[(ni * 16 + fr) * 72 + mi * 16 + fq * 4 + j] =
                        f2b(acc[mi][ni][j]);
        const int r0w = row0 + wm0;
        const int b = r0w >> 8, m0w = r0w & 255;
        const int cc0 = col0 + wn0, hh = cc0 >> 6;
        u16* dst = (u16*)Cv + coff + ((size_t)(b * 8 + hh) * 64) * 256 + m0w;
#pragma unroll
        for (int it = 0; it < 8; ++it) {
            int dl = it * 8 + (lane >> 3);
            int ml = (lane & 7) * 8;
            u16x8 v = *(const u16x8*)&Tw[dl * 72 + ml];
            *(u16x8*)&dst[(size_t)dl * 256 + ml] = v;
        }
        return;
    }

    float* Cf = (float*)Cv;
    u16* Cb = (u16*)Cv;
#pragma unroll
    for (int mi = 0; mi < 4; ++mi) {
        const int rb = row0 + wm0 + mi * 16 + fq * 4;
#pragma unroll
        for (int ni = 0; ni < 4; ++ni) {
            const int cc = col0 + wn0 + ni * 16 + fr;
            f32x4 v = acc[mi][ni];
            float bval = 0.f;
            if ((EPI == 1 || EPI == 2) && bias) bval = bias[cc];
#pragma unroll
            for (int j = 0; j < 4; ++j) {
                const long r = rb + j;
                float o = v[j] + bval;
                if (EPI == 1) {
                    Cb[coff + r * ldc + cc] = f2b(o);
                } else if (EPI == 2) {
                    Cf[coff + r * ldc + cc] = o + resid[r * ldr + cc];
                } else if (EPI == 4) {
                    Cb[coff + r * ldc + cc] = f2b(o * rowscale[r]);
                }
            }
        }
    }
}

// ---------------------------------------------------------------------------
// Batched weight transpose+convert: src f32 [K][N] -> dst bf16 [N][K].
// permN > 0: GEGLU frag-pair interleave — val n -> (n/16)*32 + n%16,
//            gate m=n-permN -> (m/16)*32 + 16 + m%16
// ---------------------------------------------------------------------------
__global__ __launch_bounds__(256) void transposeW(const float* __restrict__ src,
                                                  u16* __restrict__ dst,
                                                  int K, int N,
                                                  long srcZ, long dstZ, int permN)
{
    __shared__ float tile[64][65];
    const int t = threadIdx.x;
    const int n0 = blockIdx.x * 64, k0 = blockIdx.y * 64;
    const float* s = src + (size_t)blockIdx.z * srcZ;
    u16* d = dst + (size_t)blockIdx.z * dstZ;
#pragma unroll
    for (int i = 0; i < 16; ++i) {
        int idx = i * 256 + t;
        int rr = idx >> 6, cc = idx & 63;
        tile[rr][cc] = s[(size_t)(k0 + rr) * N + n0 + cc];
    }
    __syncthreads();
#pragma unroll
    for (int i = 0; i < 16; ++i) {
        int idx = i * 256 + t;
        int rr = idx >> 6, cc = idx & 63;
        int n = n0 + rr;
        int p = n;
        if (permN) {
            p = (n < permN) ? (((n >> 4) << 5) + (n & 15))
                            : ((((n - permN) >> 4) << 5) + 16 + ((n - permN) & 15));
        }
        d[(size_t)p * K + k0 + cc] = f2b(tile[cc][rr]);
    }
}

__global__ __launch_bounds__(256) void conv_f2b(const float* __restrict__ in,
                                                u16* __restrict__ out)
{
    size_t i = (size_t)blockIdx.x * 256 + threadIdx.x;
    float4 v = ((const float4*)in)[i];
    u16x4 o;
    o[0] = f2b(v.x); o[1] = f2b(v.y); o[2] = f2b(v.z); o[3] = f2b(v.w);
    ((u16x4*)out)[i] = o;
}

// ---------------------------------------------------------------------------
__global__ __launch_bounds__(512) void bn_colstats(const float* __restrict__ x,
                                                   float* __restrict__ cs,
                                                   float* __restrict__ cq)
{
    int c = threadIdx.x;
    int r0 = blockIdx.x * 128;
    float s = 0.f, q = 0.f;
    for (int r = 0; r < 128; ++r) {
        float v = x[(size_t)(r0 + r) * DIM + c];
        s += v; q += v * v;
    }
    atomicAdd(&cs[c], s);
    atomicAdd(&cq[c], q);
}

__global__ void bn_finalize(const float* __restrict__ cs, const float* __restrict__ cq,
                            const float* __restrict__ bw, const float* __restrict__ bb,
                            float* __restrict__ scale, float* __restrict__ shift)
{
    int c = threadIdx.x;
    float m   = cs[c] * (1.f / N_NODES);
    float var = cq[c] * (1.f / N_NODES) - m * m;
    float rs  = rsqrtf(var + LNEPS);
    float sc  = rs * bw[c];
    scale[c] = sc;
    shift[c] = bb[c] - m * sc;
}

__global__ __launch_bounds__(256) void bn_apply_b(const float* __restrict__ x,
                                                  const float* __restrict__ scale,
                                                  const float* __restrict__ shift,
                                                  u16* __restrict__ out)
{
    size_t idx = (size_t)blockIdx.x * 256 + threadIdx.x;
    int c4 = (int)(idx & 127);
    float4 v  = ((const float4*)x)[idx];
    float4 sc = ((const float4*)scale)[c4];
    float4 sh = ((const float4*)shift)[c4];
    u16x4 o;
    o[0] = f2b(v.x * sc.x + sh.x); o[1] = f2b(v.y * sc.y + sh.y);
    o[2] = f2b(v.z * sc.z + sh.z); o[3] = f2b(v.w * sc.w + sh.w);
    ((u16x4*)out)[idx] = o;
}

__global__ __launch_bounds__(256) void layernorm_b(const float* __restrict__ in,
                                                   const float* __restrict__ w,
                                                   const float* __restrict__ bsh,
                                                   u16* __restrict__ out)
{
    int lane = threadIdx.x & 63, wv = threadIdx.x >> 6;
    size_t row = (size_t)blockIdx.x * 4 + wv;
    const float* p = in + row * DIM + lane * 8;
    float4 v0 = *(const float4*)p;
    float4 v1 = *(const float4*)(p + 4);
    float s = v0.x + v0.y + v0.z + v0.w + v1.x + v1.y + v1.z + v1.w;
    float q = v0.x * v0.x + v0.y * v0.y + v0.z * v0.z + v0.w * v0.w +
              v1.x * v1.x + v1.y * v1.y + v1.z * v1.z + v1.w * v1.w;
    for (int m = 1; m < 64; m <<= 1) {
        s += __shfl_xor(s, m, 64);
        q += __shfl_xor(q, m, 64);
    }
    float mean = s * (1.f / DIM);
    float rs = rsqrtf(q * (1.f / DIM) - mean * mean + LNEPS);
    float4 w0 = *(const float4*)(w + lane * 8),   w1 = *(const float4*)(w + lane * 8 + 4);
    float4 b0 = *(const float4*)(bsh + lane * 8), b1 = *(const float4*)(bsh + lane * 8 + 4);
    u16x8 o;
    o[0] = f2b((v0.x - mean) * rs * w0.x + b0.x);
    o[1] = f2b((v0.y - mean) * rs * w0.y + b0.y);
    o[2] = f2b((v0.z - mean) * rs * w0.z + b0.z);
    o[3] = f2b((v0.w - mean) * rs * w0.w + b0.w);
    o[4] = f2b((v1.x - mean) * rs * w1.x + b1.x);
    o[5] = f2b((v1.y - mean) * rs * w1.y + b1.y);
    o[6] = f2b((v1.z - mean) * rs * w1.z + b1.z);
    o[7] = f2b((v1.w - mean) * rs * w1.w + b1.w);
    *(u16x8*)(out + row * DIM + lane * 8) = o;
}

// ---------------------------------------------------------------------------
// Fused attention, 512 threads / 8 waves (2 waves/SIMD). Per block: 512
// q-rows, one (head, batch). K [256][64], V^T [64][256] in LDS; per-wave
// swizzled P tile; 4 q-tiles of 16 rows per wave.
// ---------------------------------------------------------------------------
__global__ __launch_bounds__(512) void fused_attn(
    const u16* __restrict__ Q,    // [16384][512]
    const u16* __restrict__ Kp,   // [4096][512]
    const u16* __restrict__ Vt,   // [16][8][64][256]
    u16* __restrict__ O)          // [16384][512]
{
    __shared__ u16 Ks[256 * 64];
    __shared__ u16 Vs[64 * 256];
    __shared__ u16 Ps[8][16 * 256];

    const int t = threadIdx.x;
    const int wave = t >> 6, lane = t & 63;
    const int fr = lane & 15, fq = lane >> 4;
    const int qc = blockIdx.x, h = blockIdx.y, b = blockIdx.z;
    const int ldsW = (t & 448) * 16;   // wave * 1024 bytes

#pragma unroll
    for (int i = 0; i < 4; ++i) {
        int idx = i * 512 + t;
        int m = idx >> 3, s = idx & 7;
        gload16(Kp + (size_t)(b * MCTX + m) * 512 + h * 64 + ((s ^ (m & 7)) * 8),
                (char*)Ks + i * 8192 + ldsW);
    }
#pragma unroll
    for (int i = 0; i < 4; ++i) {
        int idx = i * 512 + t;
        int d = idx >> 5, s = idx & 31;
        gload16(Vt + (size_t)((b * 8 + h) * 64 + d) * 256 + ((s ^ (d & 7)) * 8),
                (char*)Vs + i * 8192 + ldsW);
    }
    __syncthreads();

    u16* Pw = Ps[wave];
    for (int it = 0; it < 4; ++it) {
        const int q0 = qc * 512 + it * 128 + wave * 16;
        bf16x8 aq[2];
#pragma unroll
        for (int ks = 0; ks < 2; ++ks)
            aq[ks] = *(const bf16x8*)&Q[(size_t)(b * SEQ + q0 + fr) * 512 +
                                        h * 64 + ks * 32 + fq * 8];
        f32x4 accS[16];
#pragma unroll
        for (int ni = 0; ni < 16; ++ni) accS[ni] = (f32x4){0.f, 0.f, 0.f, 0.f};
#pragma unroll
        for (int ni = 0; ni < 16; ++ni) {
            int m = ni * 16 + fr;
#pragma unroll
            for (int ks = 0; ks < 2; ++ks) {
                bf16x8 bv = *(const bf16x8*)&Ks[m * 64 + (((ks * 4 + fq) ^ (m & 7)) * 8)];
                accS[ni] = __builtin_amdgcn_mfma_f32_16x16x32_bf16(
                    aq[ks], bv, accS[ni], 0, 0, 0);
            }
        }
        const float cs = 0.125f;
#pragma unroll
        for (int j = 0; j < 4; ++j) {
            float m0 = accS[0][j];
#pragma unroll
            for (int ni = 1; ni < 16; ++ni) m0 = fmaxf(m0, accS[ni][j]);
            m0 = fmaxf(m0, __shfl_xor(m0, 1, 64));
            m0 = fmaxf(m0, __shfl_xor(m0, 2, 64));
            m0 = fmaxf(m0, __shfl_xor(m0, 4, 64));
            m0 = fmaxf(m0, __shfl_xor(m0, 8, 64));
            float s0 = 0.f;
#pragma unroll
            for (int ni = 0; ni < 16; ++ni) {
                float p = __expf((accS[ni][j] - m0) * cs);
                accS[ni][j] = p;
                s0 += p;
            }
            s0 += __shfl_xor(s0, 1, 64);
            s0 += __shfl_xor(s0, 2, 64);
            s0 += __shfl_xor(s0, 4, 64);
            s0 += __shfl_xor(s0, 8, 64);
            float inv = 1.f / s0;
#pragma unroll
            for (int ni = 0; ni < 16; ++ni) {
                int cc = ni * 16 + fr;
                int rr = fq * 4 + j;
                Pw[rr * 256 + (((cc >> 3) ^ (rr & 7)) * 8) + (cc & 7)] =
                    f2b(accS[ni][j] * inv);
            }
        }
        bf16x8 ap[8];
#pragma unroll
        for (int ks = 0; ks < 8; ++ks)
            ap[ks] = *(const bf16x8*)&Pw[fr * 256 + (((ks * 4 + fq) ^ (fr & 7)) * 8)];
        f32x4 accO[4];
#pragma unroll
        for (int ni = 0; ni < 4; ++ni) accO[ni] = (f32x4){0.f, 0.f, 0.f, 0.f};
#pragma unroll
        for (int ni = 0; ni < 4; ++ni) {
            int d = ni * 16 + fr;
#pragma unroll
            for (int ks = 0; ks < 8; ++ks) {
                bf16x8 bv = *(const bf16x8*)&Vs[d * 256 + (((ks * 4 + fq) ^ (d & 7)) * 8)];
                accO[ni] = __builtin_amdgcn_mfma_f32_16x16x32_bf16(
                    ap[ks], bv, accO[ni], 0, 0, 0);
            }
        }
#pragma unroll
        for (int ni = 0; ni < 4; ++ni)
#pragma unroll
            for (int j = 0; j < 4; ++j)
                O[(size_t)(b * SEQ + q0 + fq * 4 + j) * 512 + h * 64 + ni * 16 + fr] =
                    f2b(accO[ni][j]);
    }
}

// ---------------------------------------------------------------------------
__global__ void detect_i64(const int* __restrict__ e, int* __restrict__ flag)
{
    int idx = blockIdx.x * blockDim.x + threadIdx.x;
    if (e[2 * idx + 1] != 0) flag[0] = 1;
}

__global__ void deg_count(const int* __restrict__ eb, const int* __restrict__ flag,
                          int* __restrict__ deg)
{
    int e = blockIdx.x * blockDim.x + threadIdx.x;
    int d;
    if (flag[0]) d = eb[NEDGE + e];
    else         d = (int)((const long long*)eb)[NEDGE + e];
    atomicAdd(&deg[d], 1);
}

__global__ void dinv_k(const int* __restrict__ deg, float* __restrict__ dinv)
{
    int i = blockIdx.x * blockDim.x + threadIdx.x;
    dinv[i] = rsqrtf((float)(deg[i] + 1));
}

__global__ __launch_bounds__(1024) void scan_deg(const int* __restrict__ deg,
                                                 int* __restrict__ off)
{
    __shared__ int sums[1024];
    int t = threadIdx.x;
    int base = t * 16;
    int v[16]; int s = 0;
#pragma unroll
    for (int i = 0; i < 16; ++i) { v[i] = deg[base + i]; s += v[i]; }
    sums[t] = s;
    __syncthreads();
    for (int ofs = 1; ofs < 1024; ofs <<= 1) {
        int x = (t >= ofs) ? sums[t - ofs] : 0;
        __syncthreads();
        sums[t] += x;
        __syncthreads();
    }
    int run = (t == 0) ? 0 : sums[t - 1];
#pragma unroll
    for (int i = 0; i < 16; ++i) { off[base + i] = run; run += v[i]; }
    if (t == 1023) off[N_NODES] = run;
}

__global__ void fill_k(const int* __restrict__ eb, const int* __restrict__ flag,
                       const int* __restrict__ off, int* __restrict__ cursor,
                       int* __restrict__ csr)
{
    int e = blockIdx.x * blockDim.x + threadIdx.x;
    int s, d;
    if (flag[0]) { s = eb[e]; d = eb[NEDGE + e]; }
    else {
        const long long* p = (const long long*)eb;
        s = (int)p[e]; d = (int)p[NEDGE + e];
    }
    int pos = atomicAdd(&cursor[d], 1);
    csr[off[d] + pos] = s;
}

// h2 rows are PRE-SCALED by dinv[row]; 2-way unrolled independent row loads.
__global__ __launch_bounds__(256) void gcn_gather(
    const u16* __restrict__ h2, const int* __restrict__ csr,
    const int* __restrict__ off, const float* __restrict__ dinv,
    const float* __restrict__ bias, const float* __restrict__ addx,
    float* __restrict__ out)
{
    int lane = threadIdx.x & 63, wv = threadIdx.x >> 6;
    int d = blockIdx.x * 4 + wv;
    float a0[8], a1[8];
#pragma unroll
    for (int j = 0; j < 8; ++j) { a0[j] = 0.f; a1[j] = 0.f; }
    int e0 = off[d], e1 = off[d + 1];
    float dd = dinv[d];
    int e = e0;
    if ((e1 - e0) & 1) {
        u16x8 v = *(const u16x8*)&h2[(size_t)csr[e] * DIM + lane * 8];
#pragma unroll
        for (int j = 0; j < 8; ++j) a0[j] += b2f(v[j]);
        ++e;
    }
    for (; e < e1; e += 2) {
        int s0 = csr[e], s1 = csr[e + 1];
        u16x8 v0 = *(const u16x8*)&h2[(size_t)s0 * DIM + lane * 8];
        u16x8 v1 = *(const u16x8*)&h2[(size_t)s1 * DIM + lane * 8];
#pragma unroll
        for (int j = 0; j < 8; ++j) a0[j] += b2f(v0[j]);
#pragma unroll
        for (int j = 0; j < 8; ++j) a1[j] += b2f(v1[j]);
    }
    u16x8 vd = *(const u16x8*)&h2[(size_t)d * DIM + lane * 8];
    float o[8];
#pragma unroll
    for (int j = 0; j < 8; ++j) {
        o[j] = (a0[j] + a1[j] + b2f(vd[j])) * dd + bias[lane * 8 + j];
        if (addx) o[j] += addx[(size_t)d * DIM + lane * 8 + j];
    }
    float* op = out + (size_t)d * DIM + lane * 8;
    *(float4*)op = make_float4(o[0], o[1], o[2], o[3]);
    *(float4*)(op + 4) = make_float4(o[4], o[5], o[6], o[7]);
}

// ---------------------------------------------------------------------------
extern "C" void kernel_launch(void* const* d_in, const int* in_sizes, int n_in,
                              void* d_out, int out_size, void* d_ws, size_t ws_size,
                              hipStream_t stream)
{
    const float* x         = (const float*)d_in[0];
    const int*   edges     = (const int*)d_in[1];
    const float* cond      = (const float*)d_in[2];
    const float* bn_w      = (const float*)d_in[3];
    const float* bn_b      = (const float*)d_in[4];
    const float* gcn_in_w  = (const float*)d_in[5];
    const float* gcn_in_b  = (const float*)d_in[6];
    const float* gcn_out_w = (const float*)d_in[7];
    const float* gcn_out_b = (const float*)d_in[8];
    const float* Wq  = (const float*)d_in[9];
    const float* Wk  = (const float*)d_in[10];
    const float* Wv  = (const float*)d_in[11];
    const float* Wo  = (const float*)d_in[12];
    const float* ln2w = (const float*)d_in[13];
    const float* ln2b = (const float*)d_in[14];
    const float* ln3w = (const float*)d_in[15];
    const float* ln3b = (const float*)d_in[16];
    const float* ggw = (const float*)d_in[17];
    const float* ggb = (const float*)d_in[18];
    const float* fow = (const float*)d_in[19];
    const float* fob = (const float*)d_in[20];
    float* outp = (float*)d_out;

    char* wsb = (char*)d_ws;
    size_t wsoff = 0;
    auto alloc = [&](size_t bytes) -> void* {
        void* p = wsb + wsoff;
        wsoff = (wsoff + bytes + 255) & ~(size_t)255;
        return p;
    };
    u16*   wT    = (u16*)  alloc((size_t)17301504 * 2);
    u16*   condb = (u16*)  alloc((size_t)4096 * 512 * 2);
    float* h     = (float*)alloc((size_t)N_NODES * DIM * 4);
    u16*   t0b   = (u16*)  alloc((size_t)N_NODES * DIM * 2);
    u16*   qb    = (u16*)  alloc((size_t)N_NODES * DIM * 2);
    u16*   ob    = (u16*)  alloc((size_t)N_NODES * DIM * 2);
    u16*   kb    = (u16*)  alloc((size_t)NLAYER * 4096 * 512 * 2);          // all layers
    u16*   Vt    = (u16*)  alloc((size_t)NLAYER * BSZ * NHEAD * DHEAD * MCTX * 2);
    char*  zbase  = wsb + wsoff;
    float* colsum = (float*)alloc(DIM * 4);
    float* colsq  = (float*)alloc(DIM * 4);
    int*   deg    = (int*)  alloc(N_NODES * 4);
    int*   cursor = (int*)  alloc(N_NODES * 4);
    int*   eflag  = (int*)  alloc(256);
    size_t zbytes = (size_t)((wsb + wsoff) - zbase);
    float* bscale = (float*)alloc(DIM * 4);
    float* bshift = (float*)alloc(DIM * 4);
    float* dinv   = (float*)alloc(N_NODES * 4);
    int*   csr_off= (int*)  alloc((N_NODES + 16) * 4);
    int*   csr_src= (int*)  alloc((size_t)NEDGE * 4);

    // FFN chunking: Ab [rows][2048] bf16 ; rows stay multiple of 256
    int nch = 0;
    for (int c = 1; c <= 16; c *= 2) {
        size_t need = ((size_t)N_NODES / c) * DFF * 2;
        if (wsoff + need <= ws_size) { nch = c; break; }
    }
    if (nch == 0) { fprintf(stderr, "ws too small (%zu)\n", ws_size); return; }
    u16* Abuf = (u16*)(wsb + wsoff);

    hipMemsetAsync(zbase, 0, zbytes, stream);

    // weight transposes (batched over layers); gg uses frag-pair perm
    u16* gcnInT  = wT;
    u16* gcnOutT = gcnInT + 262144;
    u16* WqT = gcnOutT + 262144;
    u16* WkT = WqT + 4 * 262144;
    u16* WvT = WkT + 4 * 262144;
    u16* WoT = WvT + 4 * 262144;
    u16* ggT = WoT + 4 * 262144;
    u16* foT = ggT + 4 * 2097152;
    transposeW<<<dim3(8, 8, 1), 256, 0, stream>>>(gcn_in_w,  gcnInT, 512, 512, 0, 0, 0);
    transposeW<<<dim3(8, 8, 1), 256, 0, stream>>>(gcn_out_w, gcnOutT, 512, 512, 0, 0, 0);
    transposeW<<<dim3(8, 8, 4), 256, 0, stream>>>(Wq, WqT, 512, 512, 262144, 262144, 0);
    transposeW<<<dim3(8, 8, 4), 256, 0, stream>>>(Wk, WkT, 512, 512, 262144, 262144, 0);
    transposeW<<<dim3(8, 8, 4), 256, 0, stream>>>(Wv, WvT, 512, 512, 262144, 262144, 0);
    transposeW<<<dim3(8, 8, 4), 256, 0, stream>>>(Wo, WoT, 512, 512, 262144, 262144, 0);
    transposeW<<<dim3(64, 8, 4), 256, 0, stream>>>(ggw, ggT, 512, DG, 2097152, 2097152, DFF);
    transposeW<<<dim3(8, 32, 4), 256, 0, stream>>>(fow, foT, DFF, 512, 1048576, 1048576, 0);
    conv_f2b<<<2048, 256, 0, stream>>>(cond, condb);

    // BatchNorm
    bn_colstats<<<128, 512, 0, stream>>>(x, colsum, colsq);
    bn_finalize<<<1, 512, 0, stream>>>(colsum, colsq, bn_w, bn_b, bscale, bshift);
    bn_apply_b<<<(N_NODES * DIM / 4) / 256, 256, 0, stream>>>(x, bscale, bshift, t0b);

    // graph prep
    detect_i64<<<NEDGE / 256, 256, 0, stream>>>(edges, eflag);
    deg_count<<<NEDGE / 256, 256, 0, stream>>>(edges, eflag, deg);
    dinv_k<<<N_NODES / 256, 256, 0, stream>>>(deg, dinv);
    scan_deg<<<1, 1024, 0, stream>>>(deg, csr_off);
    fill_k<<<NEDGE / 256, 256, 0, stream>>>(edges, eflag, csr_off, cursor, csr_src);

    // K/V projections for ALL layers (cond is layer-invariant), batched z=4
    bgemm<1><<<dim3(4, 32, 4), 256, 0, stream>>>(
        condb, 512, WkT, 512, nullptr, nullptr, 0, nullptr, kb, 512, 512, 1,
        0, 0, 262144, 0, (long)4096 * 512, 0);
    bgemm<3><<<dim3(4, 32, 4), 256, 0, stream>>>(
        condb, 512, WvT, 512, nullptr, nullptr, 0, nullptr, Vt, 0, 512, 1,
        0, 0, 262144, 0, (long)BSZ * NHEAD * DHEAD * MCTX, 0);

    // GCN in (rows pre-scaled by dinv via EPI=4)
    bgemm<4><<<dim3(4, 128, 1), 256, 0, stream>>>(
        t0b, 512, gcnInT, 512, nullptr, nullptr, 0, dinv, qb, 512, 512, 1,
        0, 0, 0, 0, 0, 0);
    gcn_gather<<<N_NODES / 4, 256, 0, stream>>>(qb, csr_src, csr_off, dinv,
                                                gcn_in_b, nullptr, h);

    const int ffrows = N_NODES / nch;
    for (int i = 0; i < NLAYER; ++i) {
        const u16* WqTi = WqT + (size_t)i * 262144;
        const u16* WoTi = WoT + (size_t)i * 262144;
        const u16* ggTi = ggT + (size_t)i * 2097152;
        const u16* foTi = foT + (size_t)i * 1048576;
        const u16* kbi  = kb + (size_t)i * 4096 * 512;
        const u16* Vti  = Vt + (size_t)i * BSZ * NHEAD * DHEAD * MCTX;

        // attention
        layernorm_b<<<N_NODES / 4, 256, 0, stream>>>(h, ln2w + i * DIM, ln2b + i * DIM, t0b);
        bgemm<1><<<dim3(4, 128, 1), 256, 0, stream>>>(
            t0b, 512, WqTi, 512, nullptr, nullptr, 0, nullptr, qb, 512, 512, 1,
            0, 0, 0, 0, 0, 0);
        fused_attn<<<dim3(2, 8, 16), 512, 0, stream>>>(qb, kbi, Vti, ob);
        bgemm<2><<<dim3(4, 128, 1), 256, 0, stream>>>(
            ob, 512, WoTi, 512, nullptr, h, 512, nullptr, h, 512, 512, 1,
            0, 0, 0, 0, 0, 0);

        // GEGLU FFN: 256^2 unrolled GEMM with fused pair-in-thread act
        layernorm_b<<<N_NODES / 4, 256, 0, stream>>>(h, ln3w + i * DIM, ln3b + i * DIM, t0b);
        for (int c = 0; c < nch; ++c) {
            const u16* ac = t0b + (size_t)c * ffrows * 512;
            float* hc = h + (size_t)c * ffrows * 512;
            bgemm256_geglu<<<dim3(DG / 256, ffrows / 256), 512, 0, stream>>>(
                ac, 512, ggTi, 512, ggb + (size_t)i * DG, Abuf, 512);
            bgemm<2><<<dim3(4, ffrows / 128, 1), 256, 0, stream>>>(
                Abuf, 2048, foTi, 2048, fob + (size_t)i * DIM, hc, 512, nullptr,
                hc, 512, 2048, 1, 0, 0, 0, 0, 0, 0);
        }
    }

    // GCN out + residual x
    conv_f2b<<<8192, 256, 0, stream>>>(h, t0b);
    bgemm<4><<<dim3(4, 128, 1), 256, 0, stream>>>(
        t0b, 512, gcnOutT, 512, nullptr, nullptr, 0, dinv, qb, 512, 512, 1,
        0, 0, 0, 0, 0, 0);
    gcn_gather<<<N_NODES / 4, 256, 0, stream>>>(qb, csr_src, csr_off, dinv,
                                                gcn_out_b, x, outp);
}